// Round 2
// baseline (141.216 us; speedup 1.0000x reference)
//
#include <hip/hip_runtime.h>

// Reprojection multi-rig model.
// out[i] = intrs[cam]*(p_cam.xy/p_cam.z) + pps[cam] - points_2d[i]
// where p_cam = R(q)*points_3d[pi] + t,
//       q = rel_q (x) ref_q,  t = rel_t + R(rel_q)*ref_t
// Quaternions stored [x,y,z,w]; rotation p + 2*(w*(v x p) + v x (v x p)).
//
// R2: latency-bound (VALUBusy 12.8%, HBM 31%). No repack pre-kernel (R1
// showed it costs ~7us/iter since d_ws is re-poisoned every iteration).
// Instead:
//  - in-place wide gathers: ref pose = 2 overlapping dwordx4 at 7g / 7g+3
//    (dword alignment is sufficient for multi-dword global loads on CDNA);
//    point = dwordx2 + dword.  10 gather instrs/elem -> 4.
//  - 4 elems/thread, all gathers issued before any compute (4x MLP/wave)
//  - nontemporal streams so they don't evict gather tables from L2

typedef float f4  __attribute__((ext_vector_type(4)));
typedef float f2  __attribute__((ext_vector_type(2)));
typedef int   i4  __attribute__((ext_vector_type(4)));
// 4-byte-aligned vector types for the overlapping gathers
typedef float f4u __attribute__((ext_vector_type(4), aligned(4)));
typedef float f2u __attribute__((ext_vector_type(2), aligned(4)));

// ra = (ref_t.xyz, ref_q.x), rb = (ref_q.x, ref_q.y, ref_q.z, ref_q.w)
__device__ __forceinline__ f2 project_one(
    f4u ra, f4u rb, float px, float py, float pz,
    int m, int cam, float p2x, float p2y,
    const float* s_rel, const float* s_pps, const float* s_intr)
{
    float rtx = ra.x, rty = ra.y, rtz = ra.z;
    float rqx = rb.x, rqy = rb.y, rqz = rb.z, rqw = rb.w;

    // rel pose from LDS (7*m strides: gcd(7,32)=1, conflict-free-ish; counter=0)
    const float* lp = s_rel + 7 * m;
    float ltx = lp[0], lty = lp[1], ltz = lp[2];
    float lqx = lp[3], lqy = lp[4], lqz = lp[5], lqw = lp[6];

    // t = rel_t + quat_rotate(rel_q, ref_t)
    float uvx = lqy * rtz - lqz * rty;
    float uvy = lqz * rtx - lqx * rtz;
    float uvz = lqx * rty - lqy * rtx;
    float uuvx = lqy * uvz - lqz * uvy;
    float uuvy = lqz * uvx - lqx * uvz;
    float uuvz = lqx * uvy - lqy * uvx;
    float tx = ltx + rtx + 2.0f * (lqw * uvx + uuvx);
    float ty = lty + rty + 2.0f * (lqw * uvy + uuvy);
    float tz = ltz + rtz + 2.0f * (lqw * uvz + uuvz);

    // q = quat_mul(rel_q, ref_q)
    float qw = lqw * rqw - (lqx * rqx + lqy * rqy + lqz * rqz);
    float qx = lqw * rqx + rqw * lqx + (lqy * rqz - lqz * rqy);
    float qy = lqw * rqy + rqw * lqy + (lqz * rqx - lqx * rqz);
    float qz = lqw * rqz + rqw * lqz + (lqx * rqy - lqy * rqx);

    // p_cam = quat_rotate(q, p) + t
    float v2x = qy * pz - qz * py;
    float v2y = qz * px - qx * pz;
    float v2z = qx * py - qy * px;
    float w2x = qy * v2z - qz * v2y;
    float w2y = qz * v2x - qx * v2z;
    float w2z = qx * v2y - qy * v2x;
    float pcx = px + 2.0f * (qw * v2x + w2x) + tx;
    float pcy = py + 2.0f * (qw * v2y + w2y) + ty;
    float pcz = pz + 2.0f * (qw * v2z + w2z) + tz;

    float invz = 1.0f / pcz;  // IEEE divide for numpy-matching accuracy
    f2 r;
    r.x = s_intr[2 * cam]     * (pcx * invz) + s_pps[2 * cam]     - p2x;
    r.y = s_intr[2 * cam + 1] * (pcy * invz) + s_pps[2 * cam + 1] - p2y;
    return r;
}

__global__ __launch_bounds__(256) void reproj4_kernel(
    const float2* __restrict__ points_2d,
    const int*    __restrict__ camera_indices,
    const int2*   __restrict__ grouping_indices,
    const int*    __restrict__ point_indices,
    const float*  __restrict__ camera_pps,
    const float*  __restrict__ intrs,
    const float*  __restrict__ points_3d,
    const float*  __restrict__ ref_poses,
    const float*  __restrict__ rel_poses,
    float2*       __restrict__ out,
    int n)
{
    __shared__ float s_rel[56];   // 8 rel poses x 7
    __shared__ float s_pps[16];   // 8 cams x 2
    __shared__ float s_intr[16];  // 8 cams x 2
    int tid = threadIdx.x;
    if (tid < 56) s_rel[tid] = rel_poses[tid];
    if (tid < 16) { s_pps[tid] = camera_pps[tid]; s_intr[tid] = intrs[tid]; }
    __syncthreads();

    int t = blockIdx.x * blockDim.x + tid;
    int i = 4 * t;
    if (i >= n) return;

    if (i + 3 < n) {
        // ---- streaming loads, 4 elems, all dwordx4 (nontemporal) ----
        f4 p2a = __builtin_nontemporal_load((const f4*)points_2d + 2 * t);
        f4 p2b = __builtin_nontemporal_load((const f4*)points_2d + 2 * t + 1);
        i4 gma = __builtin_nontemporal_load((const i4*)grouping_indices + 2 * t);
        i4 gmb = __builtin_nontemporal_load((const i4*)grouping_indices + 2 * t + 1);
        i4 pi  = __builtin_nontemporal_load((const i4*)point_indices + t);
        i4 cm  = __builtin_nontemporal_load((const i4*)camera_indices + t);

        // ---- issue ALL 16 gather loads before any projection math ----
        const float* rp0 = ref_poses + 7 * gma.x;
        const float* rp1 = ref_poses + 7 * gma.z;
        const float* rp2 = ref_poses + 7 * gmb.x;
        const float* rp3 = ref_poses + 7 * gmb.z;
        f4u ra0 = *(const f4u*)rp0;        // [tx,ty,tz,qx]
        f4u rb0 = *(const f4u*)(rp0 + 3);  // [qx,qy,qz,qw]
        f4u ra1 = *(const f4u*)rp1;
        f4u rb1 = *(const f4u*)(rp1 + 3);
        f4u ra2 = *(const f4u*)rp2;
        f4u rb2 = *(const f4u*)(rp2 + 3);
        f4u ra3 = *(const f4u*)rp3;
        f4u rb3 = *(const f4u*)(rp3 + 3);

        const float* pp0 = points_3d + 3 * pi.x;
        const float* pp1 = points_3d + 3 * pi.y;
        const float* pp2 = points_3d + 3 * pi.z;
        const float* pp3 = points_3d + 3 * pi.w;
        f2u P0 = *(const f2u*)pp0; float pz0 = pp0[2];
        f2u P1 = *(const f2u*)pp1; float pz1 = pp1[2];
        f2u P2 = *(const f2u*)pp2; float pz2 = pp2[2];
        f2u P3 = *(const f2u*)pp3; float pz3 = pp3[2];

        // ---- 4 independent projections ----
        f2 r0 = project_one(ra0, rb0, P0.x, P0.y, pz0, gma.y, cm.x,
                            p2a.x, p2a.y, s_rel, s_pps, s_intr);
        f2 r1 = project_one(ra1, rb1, P1.x, P1.y, pz1, gma.w, cm.y,
                            p2a.z, p2a.w, s_rel, s_pps, s_intr);
        f2 r2 = project_one(ra2, rb2, P2.x, P2.y, pz2, gmb.y, cm.z,
                            p2b.x, p2b.y, s_rel, s_pps, s_intr);
        f2 r3 = project_one(ra3, rb3, P3.x, P3.y, pz3, gmb.w, cm.w,
                            p2b.z, p2b.w, s_rel, s_pps, s_intr);

        f4 oa; oa.x = r0.x; oa.y = r0.y; oa.z = r1.x; oa.w = r1.y;
        f4 ob; ob.x = r2.x; ob.y = r2.y; ob.z = r3.x; ob.w = r3.y;
        __builtin_nontemporal_store(oa, (f4*)out + 2 * t);
        __builtin_nontemporal_store(ob, (f4*)out + 2 * t + 1);
    } else {
        // ---- tail (n not divisible by 4): scalar per element ----
        for (int k = i; k < n; ++k) {
            float2 p2d = points_2d[k];
            int2   gm  = grouping_indices[k];
            int    pik = point_indices[k];
            int    cam = camera_indices[k];
            const float* rp = ref_poses + 7 * gm.x;
            f4u ra = *(const f4u*)rp;
            f4u rb = *(const f4u*)(rp + 3);
            const float* pp = points_3d + 3 * pik;
            f2 r = project_one(ra, rb, pp[0], pp[1], pp[2], gm.y, cam,
                               p2d.x, p2d.y, s_rel, s_pps, s_intr);
            out[k] = make_float2(r.x, r.y);
        }
    }
}

extern "C" void kernel_launch(void* const* d_in, const int* in_sizes, int n_in,
                              void* d_out, int out_size, void* d_ws, size_t ws_size,
                              hipStream_t stream) {
    const float2* points_2d       = (const float2*)d_in[0];
    const int*    camera_indices  = (const int*)d_in[1];
    const int2*   grouping        = (const int2*)d_in[2];
    const int*    point_indices   = (const int*)d_in[3];
    const float*  camera_pps      = (const float*)d_in[4];
    const float*  intrs           = (const float*)d_in[5];
    const float*  points_3d       = (const float*)d_in[6];
    const float*  ref_poses       = (const float*)d_in[7];
    const float*  rel_poses       = (const float*)d_in[8];
    float2*       out             = (float2*)d_out;

    int n = in_sizes[1];  // N observations (camera_indices is (N,))
    int threads = (n + 3) / 4;
    int blocks = (threads + 255) / 256;
    reproj4_kernel<<<blocks, 256, 0, stream>>>(
        points_2d, camera_indices, grouping, point_indices,
        camera_pps, intrs, points_3d, ref_poses, rel_poses, out, n);
}

// Round 3
// 140.995 us; speedup vs baseline: 1.0016x; 1.0016x over previous
//
#include <hip/hip_runtime.h>

// Reprojection multi-rig model.
// out[i] = intrs[cam]*(p_cam.xy/p_cam.z) + pps[cam] - points_2d[i]
// where p_cam = R(q)*points_3d[pi] + t,
//       q = rel_q (x) ref_q,  t = rel_t + R(rel_q)*ref_t
// Quaternions stored [x,y,z,w]; rotation p + 2*(w*(v x p) + v x (v x p)).
//
// R3 model: per-CU outstanding-line cap (R2: 4x per-wave MLP gave ZERO gain;
// occupancy drop hurt). Rate ~ cap/(latency * lines_per_elem). So:
//  - pre-compose the 80000 (group,member) poses into a 32B-aligned d_ws
//    table (2.56 MB -> L2-resident on every XCD). Main-kernel pose gather
//    becomes exactly 1 line at L2-hit latency, and ~40 VALU compose ops
//    leave the critical path.  lines/elem 2.5 -> 2.1.
//  - main kernel keeps R0's proven shape: 1 elem/thread, 256-thr blocks,
//    7813 blocks (30/CU -> good occupancy), nontemporal streams.

typedef float f4  __attribute__((ext_vector_type(4)));
typedef float f2  __attribute__((ext_vector_type(2)));
// 4-byte-aligned vector type for in-place overlapping loads
typedef float f4u __attribute__((ext_vector_type(4), aligned(4)));

enum { NGRP = 10000, NPOS = 8 };  // fixed by problem spec

// ---------------------------------------------------------------- compose ---
// ws[(g*8+m)] = { t.xyz, q.x } { q.y, q.z, q.w, 0 }  (32B/record, aligned)
__global__ __launch_bounds__(256) void compose_kernel(
    const float* __restrict__ ref_poses,
    const float* __restrict__ rel_poses,
    f4* __restrict__ ws)
{
    int j = blockIdx.x * blockDim.x + threadIdx.x;
    if (j >= NGRP * NPOS) return;
    int g = j >> 3, m = j & 7;

    const float* rp = ref_poses + 7 * g;
    f4u ra = *(const f4u*)rp;        // [tx,ty,tz,qx]
    f4u rb = *(const f4u*)(rp + 3);  // [qx,qy,qz,qw]
    float rtx = ra.x, rty = ra.y, rtz = ra.z;
    float rqx = rb.x, rqy = rb.y, rqz = rb.z, rqw = rb.w;

    const float* lp = rel_poses + 7 * m;   // 8 poses, L1-hot
    float ltx = lp[0], lty = lp[1], ltz = lp[2];
    float lqx = lp[3], lqy = lp[4], lqz = lp[5], lqw = lp[6];

    // t = rel_t + quat_rotate(rel_q, ref_t)
    float uvx = lqy * rtz - lqz * rty;
    float uvy = lqz * rtx - lqx * rtz;
    float uvz = lqx * rty - lqy * rtx;
    float uuvx = lqy * uvz - lqz * uvy;
    float uuvy = lqz * uvx - lqx * uvz;
    float uuvz = lqx * uvy - lqy * uvx;
    float tx = ltx + rtx + 2.0f * (lqw * uvx + uuvx);
    float ty = lty + rty + 2.0f * (lqw * uvy + uuvy);
    float tz = ltz + rtz + 2.0f * (lqw * uvz + uuvz);

    // q = quat_mul(rel_q, ref_q)
    float qw = lqw * rqw - (lqx * rqx + lqy * rqy + lqz * rqz);
    float qx = lqw * rqx + rqw * lqx + (lqy * rqz - lqz * rqy);
    float qy = lqw * rqy + rqw * lqy + (lqz * rqx - lqx * rqz);
    float qz = lqw * rqz + rqw * lqz + (lqx * rqy - lqy * rqx);

    f4 a; a.x = tx; a.y = ty; a.z = tz; a.w = qx;
    f4 b; b.x = qy; b.y = qz; b.z = qw; b.w = 0.0f;
    ws[2 * j]     = a;
    ws[2 * j + 1] = b;
}

// ------------------------------------------------------------- projection ---
// ca = (t.xyz, q.x), cb = (q.y, q.z, q.w, _)
__device__ __forceinline__ f2 project_composed(
    f4 ca, f4 cb, float px, float py, float pz,
    int cam, float p2x, float p2y,
    const float* s_pps, const float* s_intr)
{
    float tx = ca.x, ty = ca.y, tz = ca.z;
    float qx = ca.w, qy = cb.x, qz = cb.y, qw = cb.z;

    // p_cam = quat_rotate(q, p) + t
    float v2x = qy * pz - qz * py;
    float v2y = qz * px - qx * pz;
    float v2z = qx * py - qy * px;
    float w2x = qy * v2z - qz * v2y;
    float w2y = qz * v2x - qx * v2z;
    float w2z = qx * v2y - qy * v2x;
    float pcx = px + 2.0f * (qw * v2x + w2x) + tx;
    float pcy = py + 2.0f * (qw * v2y + w2y) + ty;
    float pcz = pz + 2.0f * (qw * v2z + w2z) + tz;

    float invz = 1.0f / pcz;  // IEEE divide for numpy-matching accuracy
    f2 r;
    r.x = s_intr[2 * cam]     * (pcx * invz) + s_pps[2 * cam]     - p2x;
    r.y = s_intr[2 * cam + 1] * (pcy * invz) + s_pps[2 * cam + 1] - p2y;
    return r;
}

// ------------------------------------------------------------ main kernel ---
__global__ __launch_bounds__(256) void reproj_kernel(
    const float2* __restrict__ points_2d,
    const int*    __restrict__ camera_indices,
    const int2*   __restrict__ grouping_indices,
    const int*    __restrict__ point_indices,
    const float*  __restrict__ camera_pps,
    const float*  __restrict__ intrs,
    const float*  __restrict__ points_3d,
    const f4*     __restrict__ composed,
    float2*       __restrict__ out,
    int n)
{
    __shared__ float s_pps[16];   // 8 cams x 2
    __shared__ float s_intr[16];  // 8 cams x 2
    int tid = threadIdx.x;
    if (tid < 16) { s_pps[tid] = camera_pps[tid]; s_intr[tid] = intrs[tid]; }
    __syncthreads();

    int i = blockIdx.x * blockDim.x + tid;
    if (i >= n) return;

    // Coalesced streaming loads (nontemporal: don't evict gather tables)
    float2 p2d;
    { f2 v = __builtin_nontemporal_load((const f2*)points_2d + i);
      p2d.x = v.x; p2d.y = v.y; }
    int2 gm;
    { typedef int i2v __attribute__((ext_vector_type(2)));
      i2v v = __builtin_nontemporal_load((const i2v*)grouping_indices + i);
      gm.x = v.x; gm.y = v.y; }
    int pi  = __builtin_nontemporal_load(point_indices + i);
    int cam = __builtin_nontemporal_load(camera_indices + i);

    // Composed pose: one 64B line, 32B-aligned, 2.56MB table (L2-resident)
    int c = 8 * gm.x + gm.y;
    f4 ca = composed[2 * c];
    f4 cb = composed[2 * c + 1];

    // 3D point gather (6 MB table). dwordx3, 12B stride.
    const float* pp = points_3d + 3 * pi;
    float px = pp[0], py = pp[1], pz = pp[2];

    f2 r = project_composed(ca, cb, px, py, pz, cam, p2d.x, p2d.y,
                            s_pps, s_intr);
    f2 o; o.x = r.x; o.y = r.y;
    __builtin_nontemporal_store(o, (f2*)out + i);
}

// -------------------------------------------------- fallback (no ws) -------
__global__ __launch_bounds__(256) void reproj_inline_kernel(
    const float2* __restrict__ points_2d,
    const int*    __restrict__ camera_indices,
    const int2*   __restrict__ grouping_indices,
    const int*    __restrict__ point_indices,
    const float*  __restrict__ camera_pps,
    const float*  __restrict__ intrs,
    const float*  __restrict__ points_3d,
    const float*  __restrict__ ref_poses,
    const float*  __restrict__ rel_poses,
    float2*       __restrict__ out,
    int n)
{
    __shared__ float s_rel[56];
    __shared__ float s_pps[16];
    __shared__ float s_intr[16];
    int tid = threadIdx.x;
    if (tid < 56) s_rel[tid] = rel_poses[tid];
    if (tid < 16) { s_pps[tid] = camera_pps[tid]; s_intr[tid] = intrs[tid]; }
    __syncthreads();

    int i = blockIdx.x * blockDim.x + tid;
    if (i >= n) return;

    int2  gm  = grouping_indices[i];
    int   pi  = point_indices[i];
    int   cam = camera_indices[i];
    float2 p2d = points_2d[i];

    const float* rp = ref_poses + 7 * gm.x;
    float rtx = rp[0], rty = rp[1], rtz = rp[2];
    float rqx = rp[3], rqy = rp[4], rqz = rp[5], rqw = rp[6];
    const float* lp = s_rel + 7 * gm.y;
    float ltx = lp[0], lty = lp[1], ltz = lp[2];
    float lqx = lp[3], lqy = lp[4], lqz = lp[5], lqw = lp[6];

    float uvx = lqy * rtz - lqz * rty;
    float uvy = lqz * rtx - lqx * rtz;
    float uvz = lqx * rty - lqy * rtx;
    float uuvx = lqy * uvz - lqz * uvy;
    float uuvy = lqz * uvx - lqx * uvz;
    float uuvz = lqx * uvy - lqy * uvx;
    float tx = ltx + rtx + 2.0f * (lqw * uvx + uuvx);
    float ty = lty + rty + 2.0f * (lqw * uvy + uuvy);
    float tz = ltz + rtz + 2.0f * (lqw * uvz + uuvz);

    float qw = lqw * rqw - (lqx * rqx + lqy * rqy + lqz * rqz);
    float qx = lqw * rqx + rqw * lqx + (lqy * rqz - lqz * rqy);
    float qy = lqw * rqy + rqw * lqy + (lqz * rqx - lqx * rqz);
    float qz = lqw * rqz + rqw * lqz + (lqx * rqy - lqy * rqx);

    const float* pp = points_3d + 3 * pi;
    float px = pp[0], py = pp[1], pz = pp[2];

    f4 ca; ca.x = tx; ca.y = ty; ca.z = tz; ca.w = qx;
    f4 cb; cb.x = qy; cb.y = qz; cb.z = qw; cb.w = 0.0f;
    f2 r = project_composed(ca, cb, px, py, pz, cam, p2d.x, p2d.y,
                            s_pps, s_intr);
    out[i] = make_float2(r.x, r.y);
}

// --------------------------------------------------------------- launcher ---
extern "C" void kernel_launch(void* const* d_in, const int* in_sizes, int n_in,
                              void* d_out, int out_size, void* d_ws, size_t ws_size,
                              hipStream_t stream) {
    const float2* points_2d       = (const float2*)d_in[0];
    const int*    camera_indices  = (const int*)d_in[1];
    const int2*   grouping        = (const int2*)d_in[2];
    const int*    point_indices   = (const int*)d_in[3];
    const float*  camera_pps      = (const float*)d_in[4];
    const float*  intrs           = (const float*)d_in[5];
    const float*  points_3d       = (const float*)d_in[6];
    const float*  ref_poses       = (const float*)d_in[7];
    const float*  rel_poses       = (const float*)d_in[8];
    float2*       out             = (float2*)d_out;

    int n = in_sizes[1];  // N observations (camera_indices is (N,))
    int blocks = (n + 255) / 256;

    size_t need = (size_t)NGRP * NPOS * 32;  // 2.56 MB
    if (d_ws && ws_size >= need) {
        f4* ws = (f4*)d_ws;
        int cthreads = NGRP * NPOS;
        compose_kernel<<<(cthreads + 255) / 256, 256, 0, stream>>>(
            ref_poses, rel_poses, ws);
        reproj_kernel<<<blocks, 256, 0, stream>>>(
            points_2d, camera_indices, grouping, point_indices,
            camera_pps, intrs, points_3d, ws, out, n);
    } else {
        reproj_inline_kernel<<<blocks, 256, 0, stream>>>(
            points_2d, camera_indices, grouping, point_indices,
            camera_pps, intrs, points_3d, ref_poses, rel_poses, out, n);
    }
}

// Round 4
// 132.802 us; speedup vs baseline: 1.0634x; 1.0617x over previous
//
#include <hip/hip_runtime.h>

// Reprojection multi-rig model.
// out[i] = intrs[cam]*(p_cam.xy/p_cam.z) + pps[cam] - points_2d[i]
// where p_cam = R(q)*points_3d[pi] + t,
//       q = rel_q (x) ref_q,  t = rel_t + R(rel_q)*ref_t
// Quaternions stored [x,y,z,w]; rotation p + 2*(w*(v x p) + v x (v x p)).
//
// R4 model: per-CU line-miss service rate — time ~ unique gather lines/elem
// (R2: 4x MLP null; R3: -40 VALU/elem null, +footprint hurt).
// Change vs R0 champion: ONE thing — ref_poses repacked to 32B-aligned
// records in d_ws (320 KB, L2-warm, ~0.1us repack). 28B @ 32B align never
// straddles a 64B line: pose lines/elem 1.33 -> 1.00.
// Everything else identical to R0 (1 elem/thread, plain streams, same FP
// order -> same absmax).

typedef float f4 __attribute__((ext_vector_type(4)));

enum { NGRP = 10000 };  // fixed by problem spec

// ---------------------------------------------------------------- repack ---
// ws[2g+0] = { tx, ty, tz, qx }, ws[2g+1] = { qy, qz, qw, 0 }
__global__ __launch_bounds__(256) void repack_ref_kernel(
    const float* __restrict__ ref_poses,
    f4* __restrict__ ws)
{
    int g = blockIdx.x * blockDim.x + threadIdx.x;
    if (g >= NGRP) return;
    const float* rp = ref_poses + 7 * g;
    f4 a; a.x = rp[0]; a.y = rp[1]; a.z = rp[2]; a.w = rp[3];
    f4 b; b.x = rp[4]; b.y = rp[5]; b.z = rp[6]; b.w = 0.0f;
    ws[2 * g]     = a;
    ws[2 * g + 1] = b;
}

// ------------------------------------------------------------ main kernel ---
__global__ __launch_bounds__(256) void reproj_kernel(
    const float2* __restrict__ points_2d,
    const int*    __restrict__ camera_indices,
    const int2*   __restrict__ grouping_indices,
    const int*    __restrict__ point_indices,
    const float*  __restrict__ camera_pps,
    const float*  __restrict__ intrs,
    const float*  __restrict__ points_3d,
    const f4*     __restrict__ refpk,   // 32B-aligned ref poses
    const float*  __restrict__ rel_poses,
    float2*       __restrict__ out,
    int n)
{
    // Tiny read-only tables -> LDS (broadcast reads)
    __shared__ float s_rel[56];   // 8 rel poses x 7
    __shared__ float s_pps[16];   // 8 cams x 2
    __shared__ float s_intr[16];  // 8 cams x 2
    int tid = threadIdx.x;
    if (tid < 56) s_rel[tid] = rel_poses[tid];
    if (tid < 16) { s_pps[tid] = camera_pps[tid]; s_intr[tid] = intrs[tid]; }
    __syncthreads();

    int i = blockIdx.x * blockDim.x + tid;
    if (i >= n) return;

    // Coalesced streaming loads (same as R0 champion)
    int2  gm  = grouping_indices[i];
    int   pi  = point_indices[i];
    int   cam = camera_indices[i];
    float2 p2d = points_2d[i];

    // ref pose gather: one 64B line always (32B-aligned record), L2-warm
    f4 ca = refpk[2 * gm.x];      // [tx,ty,tz,qx]
    f4 cb = refpk[2 * gm.x + 1];  // [qy,qz,qw,0] — same line, L1-hit
    float rtx = ca.x, rty = ca.y, rtz = ca.z;
    float rqx = ca.w, rqy = cb.x, rqz = cb.y, rqw = cb.z;

    // rel pose from LDS
    const float* lp = s_rel + 7 * gm.y;
    float ltx = lp[0], lty = lp[1], ltz = lp[2];
    float lqx = lp[3], lqy = lp[4], lqz = lp[5], lqw = lp[6];

    // t = rel_t + quat_rotate(rel_q, ref_t)
    float uvx = lqy * rtz - lqz * rty;
    float uvy = lqz * rtx - lqx * rtz;
    float uvz = lqx * rty - lqy * rtx;
    float uuvx = lqy * uvz - lqz * uvy;
    float uuvy = lqz * uvx - lqx * uvz;
    float uuvz = lqx * uvy - lqy * uvx;
    float tx = ltx + rtx + 2.0f * (lqw * uvx + uuvx);
    float ty = lty + rty + 2.0f * (lqw * uvy + uuvy);
    float tz = ltz + rtz + 2.0f * (lqw * uvz + uuvz);

    // q = quat_mul(rel_q, ref_q)
    float qw = lqw * rqw - (lqx * rqx + lqy * rqy + lqz * rqz);
    float qx = lqw * rqx + rqw * lqx + (lqy * rqz - lqz * rqy);
    float qy = lqw * rqy + rqw * lqy + (lqz * rqx - lqx * rqz);
    float qz = lqw * rqz + rqw * lqz + (lqx * rqy - lqy * rqx);

    // 3D point gather (6 MB table, L2-partial). dwordx3, 12B stride.
    const float* pp = points_3d + 3 * pi;
    float px = pp[0], py = pp[1], pz = pp[2];

    // p_cam = quat_rotate(q, p) + t
    float v2x = qy * pz - qz * py;
    float v2y = qz * px - qx * pz;
    float v2z = qx * py - qy * px;
    float w2x = qy * v2z - qz * v2y;
    float w2y = qz * v2x - qx * v2z;
    float w2z = qx * v2y - qy * v2x;
    float pcx = px + 2.0f * (qw * v2x + w2x) + tx;
    float pcy = py + 2.0f * (qw * v2y + w2y) + ty;
    float pcz = pz + 2.0f * (qw * v2z + w2z) + tz;

    float invz = 1.0f / pcz;  // IEEE divide for numpy-matching accuracy
    float ux = s_intr[2 * cam]     * (pcx * invz) + s_pps[2 * cam];
    float uy = s_intr[2 * cam + 1] * (pcy * invz) + s_pps[2 * cam + 1];

    out[i] = make_float2(ux - p2d.x, uy - p2d.y);
}

// -------------------------------------------------- fallback (no ws) -------
__global__ __launch_bounds__(256) void reproj_inline_kernel(
    const float2* __restrict__ points_2d,
    const int*    __restrict__ camera_indices,
    const int2*   __restrict__ grouping_indices,
    const int*    __restrict__ point_indices,
    const float*  __restrict__ camera_pps,
    const float*  __restrict__ intrs,
    const float*  __restrict__ points_3d,
    const float*  __restrict__ ref_poses,
    const float*  __restrict__ rel_poses,
    float2*       __restrict__ out,
    int n)
{
    __shared__ float s_rel[56];
    __shared__ float s_pps[16];
    __shared__ float s_intr[16];
    int tid = threadIdx.x;
    if (tid < 56) s_rel[tid] = rel_poses[tid];
    if (tid < 16) { s_pps[tid] = camera_pps[tid]; s_intr[tid] = intrs[tid]; }
    __syncthreads();

    int i = blockIdx.x * blockDim.x + tid;
    if (i >= n) return;

    int2  gm  = grouping_indices[i];
    int   pi  = point_indices[i];
    int   cam = camera_indices[i];
    float2 p2d = points_2d[i];

    const float* rp = ref_poses + 7 * gm.x;
    float rtx = rp[0], rty = rp[1], rtz = rp[2];
    float rqx = rp[3], rqy = rp[4], rqz = rp[5], rqw = rp[6];
    const float* lp = s_rel + 7 * gm.y;
    float ltx = lp[0], lty = lp[1], ltz = lp[2];
    float lqx = lp[3], lqy = lp[4], lqz = lp[5], lqw = lp[6];

    float uvx = lqy * rtz - lqz * rty;
    float uvy = lqz * rtx - lqx * rtz;
    float uvz = lqx * rty - lqy * rtx;
    float uuvx = lqy * uvz - lqz * uvy;
    float uuvy = lqz * uvx - lqx * uvz;
    float uuvz = lqx * uvy - lqy * uvx;
    float tx = ltx + rtx + 2.0f * (lqw * uvx + uuvx);
    float ty = lty + rty + 2.0f * (lqw * uvy + uuvy);
    float tz = ltz + rtz + 2.0f * (lqw * uvz + uuvz);

    float qw = lqw * rqw - (lqx * rqx + lqy * rqy + lqz * rqz);
    float qx = lqw * rqx + rqw * lqx + (lqy * rqz - lqz * rqy);
    float qy = lqw * rqy + rqw * lqy + (lqz * rqx - lqx * rqz);
    float qz = lqw * rqz + rqw * lqz + (lqx * rqy - lqy * rqx);

    const float* pp = points_3d + 3 * pi;
    float px = pp[0], py = pp[1], pz = pp[2];

    float v2x = qy * pz - qz * py;
    float v2y = qz * px - qx * pz;
    float v2z = qx * py - qy * px;
    float w2x = qy * v2z - qz * v2y;
    float w2y = qz * v2x - qx * v2z;
    float w2z = qx * v2y - qy * v2x;
    float pcx = px + 2.0f * (qw * v2x + w2x) + tx;
    float pcy = py + 2.0f * (qw * v2y + w2y) + ty;
    float pcz = pz + 2.0f * (qw * v2z + w2z) + tz;

    float invz = 1.0f / pcz;
    float ux = s_intr[2 * cam]     * (pcx * invz) + s_pps[2 * cam];
    float uy = s_intr[2 * cam + 1] * (pcy * invz) + s_pps[2 * cam + 1];

    out[i] = make_float2(ux - p2d.x, uy - p2d.y);
}

// --------------------------------------------------------------- launcher ---
extern "C" void kernel_launch(void* const* d_in, const int* in_sizes, int n_in,
                              void* d_out, int out_size, void* d_ws, size_t ws_size,
                              hipStream_t stream) {
    const float2* points_2d       = (const float2*)d_in[0];
    const int*    camera_indices  = (const int*)d_in[1];
    const int2*   grouping        = (const int2*)d_in[2];
    const int*    point_indices   = (const int*)d_in[3];
    const float*  camera_pps      = (const float*)d_in[4];
    const float*  intrs           = (const float*)d_in[5];
    const float*  points_3d       = (const float*)d_in[6];
    const float*  ref_poses       = (const float*)d_in[7];
    const float*  rel_poses       = (const float*)d_in[8];
    float2*       out             = (float2*)d_out;

    int n = in_sizes[1];  // N observations (camera_indices is (N,))
    int blocks = (n + 255) / 256;

    size_t need = (size_t)NGRP * 32;  // 320 KB
    if (d_ws && ws_size >= need) {
        f4* ws = (f4*)d_ws;
        repack_ref_kernel<<<(NGRP + 255) / 256, 256, 0, stream>>>(ref_poses, ws);
        reproj_kernel<<<blocks, 256, 0, stream>>>(
            points_2d, camera_indices, grouping, point_indices,
            camera_pps, intrs, points_3d, ws, rel_poses, out, n);
    } else {
        reproj_inline_kernel<<<blocks, 256, 0, stream>>>(
            points_2d, camera_indices, grouping, point_indices,
            camera_pps, intrs, points_3d, ref_poses, rel_poses, out, n);
    }
}